// Round 3
// baseline (38.899 us; speedup 1.0000x reference)
//
#include <hip/hip_runtime.h>
#include <math.h>

#define Hh 64
#define Ww 64
#define Nn 512
#define Bb 32
#define NCHUNK 4
#define CHUNK (Nn / NCHUNK)       // 128
#define NPIX (Hh * Ww)            // 4096
#define OUTSZ (Bb * 3 * NPIX)     // 393216 floats

// params[b][n][12] = { q0,q1,q2,q3,q4,q5, ocr,ocg,ocb, pad,pad,pad }
// sigma-exponent (exp2 domain): q0 + q1*fx + q2*fy + q3*fx^2 + q4*fx*fy + q5*fy^2
__global__ __launch_bounds__(256) void gs_prep(const float* __restrict__ data,
                                               const float* __restrict__ opacity,
                                               float* __restrict__ params) {
    int i = blockIdx.x * 256 + threadIdx.x;   // i in [0, B*N)
    if (i >= Bb * Nn) return;
    int n = i & (Nn - 1);

    const float4* dp = (const float4*)(data) + (size_t)i * 2;
    float4 d0 = dp[0];   // data[...,0..3]
    float4 d1 = dp[1];   // data[...,4..7]

    float xy0 = tanhf(d0.x);
    float xy1 = tanhf(d0.y);
    float s0 = fabsf(d0.z) + 0.3f;
    float s1 = fabsf(d0.w) + 0.3f;
    float theta = (1.0f / (1.0f + expf(-d1.x))) * (2.0f * (float)M_PI);
    float c = cosf(theta);
    float s = sinf(theta);

    float px = 0.5f * ((xy0 + 1.0f) * (float)Ww - 1.0f);
    float py = 0.5f * ((xy1 + 1.0f) * (float)Hh - 1.0f);

    float s0sq = s0 * s0, s1sq = s1 * s1;
    float cov_a = c * c * s0sq + s * s * s1sq;
    float cov_b = c * s * (s0sq - s1sq);
    float cov_c = s * s * s0sq + c * c * s1sq;
    float det = cov_a * cov_c - cov_b * cov_b;
    float inv = 1.0f / det;
    float con_a = cov_c * inv;
    float con_b = -cov_b * inv;
    float con_c = cov_a * inv;

    const float L2E = 1.4426950408889634f;   // log2(e)
    float a2 = -0.5f * con_a * L2E;          // coeff of dx^2 (exp2 domain)
    float b2 = -con_b * L2E;                 // coeff of dx*dy
    float c2 = -0.5f * con_c * L2E;          // coeff of dy^2

    // expand around (px,py): dx = fx-px, dy = fy-py
    float q3 = a2, q4 = b2, q5 = c2;
    float q1 = -(2.0f * a2 * px + b2 * py);
    float q2 = -(2.0f * c2 * py + b2 * px);
    float q0 = a2 * px * px + b2 * px * py + c2 * py * py;

    float op = opacity[n];

    float4* outp = (float4*)(params) + (size_t)i * 3;
    outp[0] = make_float4(q0, q1, q2, q3);
    outp[1] = make_float4(q4, q5, op * d1.y, op * d1.z);
    outp[2] = make_float4(op * d1.w, 0.0f, 0.0f, 0.0f);
}

// One thread per pixel, one block per (batch, pixel-group, N-chunk).
// 2048 blocks -> 8192 waves -> full occupancy at VGPR~16.
// Writes partials[chunk][b][c][pix] with plain stores (no init needed).
__global__ __launch_bounds__(256) void gs_render(const float* __restrict__ params,
                                                 float* __restrict__ partials) {
    int chunk = blockIdx.x & (NCHUNK - 1);
    int grp   = (blockIdx.x >> 2) & 15;
    int b     = blockIdx.x >> 6;
    int pix   = (grp << 8) | threadIdx.x;              // 0..4095
    float fx = (float)(pix & 63);
    float fy = (float)(pix >> 6);

    const float4* pp = (const float4*)(params + (size_t)b * (Nn * 12)) +
                       (size_t)chunk * CHUNK * 3;

    float accr = 0.0f, accg = 0.0f, accb = 0.0f;
#pragma unroll 4
    for (int n = 0; n < CHUNK; ++n) {
        float4 A = pp[3 * n];        // q0,q1,q2,q3
        float4 Bv = pp[3 * n + 1];   // q4,q5,ocr,ocg
        float  ob = pp[3 * n + 2].x; // ocb
        float a = fmaf(A.w, fx, A.y);      // q3*fx + q1
        a = fmaf(Bv.x, fy, a);             // + q4*fy
        float sgm = fmaf(a, fx, A.x);      // *fx + q0
        float bq = fmaf(Bv.y, fy, A.z);    // q5*fy + q2
        sgm = fmaf(bq, fy, sgm);           // + (q5*fy+q2)*fy
        float e = __builtin_amdgcn_exp2f(sgm);
        accr = fmaf(e, Bv.z, accr);
        accg = fmaf(e, Bv.w, accg);
        accb = fmaf(e, ob, accb);
    }

    size_t base = (size_t)chunk * OUTSZ + (size_t)b * 3 * NPIX + (size_t)pix;
    partials[base]            = accr;
    partials[base + NPIX]     = accg;
    partials[base + 2 * NPIX] = accb;
}

// Sum the 4 chunk partials into d_out. float4-vectorized, fully coalesced.
__global__ __launch_bounds__(256) void gs_reduce(const float* __restrict__ partials,
                                                 float* __restrict__ out) {
    int i = blockIdx.x * 256 + threadIdx.x;   // i in [0, OUTSZ/4)
    const float4* p0 = (const float4*)(partials);
    const float4* p1 = (const float4*)(partials + OUTSZ);
    const float4* p2 = (const float4*)(partials + 2 * OUTSZ);
    const float4* p3 = (const float4*)(partials + 3 * OUTSZ);
    float4 a = p0[i], b = p1[i], c = p2[i], d = p3[i];
    float4 r;
    r.x = (a.x + b.x) + (c.x + d.x);
    r.y = (a.y + b.y) + (c.y + d.y);
    r.z = (a.z + b.z) + (c.z + d.z);
    r.w = (a.w + b.w) + (c.w + d.w);
    ((float4*)out)[i] = r;
}

extern "C" void kernel_launch(void* const* d_in, const int* in_sizes, int n_in,
                              void* d_out, int out_size, void* d_ws, size_t ws_size,
                              hipStream_t stream) {
    const float* data    = (const float*)d_in[0];
    const float* opacity = (const float*)d_in[1];
    float* params   = (float*)d_ws;                       // B*N*12*4 = 768 KB
    float* partials = (float*)d_ws + (size_t)Bb * Nn * 12; // 4*393216*4 = 6.3 MB
    float* out      = (float*)d_out;

    gs_prep<<<(Bb * Nn + 255) / 256, 256, 0, stream>>>(data, opacity, params);
    gs_render<<<Bb * 16 * NCHUNK, 256, 0, stream>>>(params, partials);
    gs_reduce<<<OUTSZ / 4 / 256, 256, 0, stream>>>(partials, out);
}

// Round 4
// 33.959 us; speedup vs baseline: 1.1455x; 1.1455x over previous
//
#include <hip/hip_runtime.h>
#include <math.h>

#define Hh 64
#define Ww 64
#define Nn 512
#define Bb 32
#define NCHUNK 4
#define CHUNK (Nn / NCHUNK)       // 128
#define NPIX (Hh * Ww)            // 4096
#define OUTSZ (Bb * 3 * NPIX)     // 393216 floats

// SoA params (exp2-domain monomial form):
//   qA[b*Nn+n] = { q0, q1, q2, q3 }
//   qB[b*Nn+n] = { q4, q5, ocr, ocg }
//   qC[b*Nn+n] = ocb
// sigma-exponent: q0 + q1*fx + q2*fy + q3*fx^2 + q4*fx*fy + q5*fy^2
__global__ __launch_bounds__(256) void gs_prep(const float* __restrict__ data,
                                               const float* __restrict__ opacity,
                                               float4* __restrict__ qA,
                                               float4* __restrict__ qB,
                                               float*  __restrict__ qC) {
    int i = blockIdx.x * 256 + threadIdx.x;   // i in [0, B*N)
    if (i >= Bb * Nn) return;
    int n = i & (Nn - 1);

    const float4* dp = (const float4*)(data) + (size_t)i * 2;
    float4 d0 = dp[0];   // data[...,0..3]
    float4 d1 = dp[1];   // data[...,4..7]

    float xy0 = tanhf(d0.x);
    float xy1 = tanhf(d0.y);
    float s0 = fabsf(d0.z) + 0.3f;
    float s1 = fabsf(d0.w) + 0.3f;
    float theta = (1.0f / (1.0f + expf(-d1.x))) * (2.0f * (float)M_PI);
    float c = cosf(theta);
    float s = sinf(theta);

    float px = 0.5f * ((xy0 + 1.0f) * (float)Ww - 1.0f);
    float py = 0.5f * ((xy1 + 1.0f) * (float)Hh - 1.0f);

    float s0sq = s0 * s0, s1sq = s1 * s1;
    float cov_a = c * c * s0sq + s * s * s1sq;
    float cov_b = c * s * (s0sq - s1sq);
    float cov_c = s * s * s0sq + c * c * s1sq;
    float det = cov_a * cov_c - cov_b * cov_b;
    float inv = 1.0f / det;
    float con_a = cov_c * inv;
    float con_b = -cov_b * inv;
    float con_c = cov_a * inv;

    const float L2E = 1.4426950408889634f;   // log2(e)
    float a2 = -0.5f * con_a * L2E;          // dx^2 coeff (exp2 domain)
    float b2 = -con_b * L2E;                 // dx*dy coeff
    float c2 = -0.5f * con_c * L2E;          // dy^2 coeff

    // expand around (px,py)
    float q3 = a2, q4 = b2, q5 = c2;
    float q1 = -(2.0f * a2 * px + b2 * py);
    float q2 = -(2.0f * c2 * py + b2 * px);
    float q0 = a2 * px * px + b2 * px * py + c2 * py * py;

    float op = opacity[n];

    qA[i] = make_float4(q0, q1, q2, q3);
    qB[i] = make_float4(q4, q5, op * d1.y, op * d1.z);
    qC[i] = op * d1.w;
}

// One thread per pixel, one block per (batch, pixel-group, N-chunk).
// Params for the block's 128 gaussians staged in LDS (4.5 KB); inner loop
// reads LDS with uniform-address broadcast (conflict-free, low latency).
__global__ __launch_bounds__(256) void gs_render(const float4* __restrict__ qA,
                                                 const float4* __restrict__ qB,
                                                 const float*  __restrict__ qC,
                                                 float* __restrict__ partials) {
    __shared__ float4 sA[CHUNK];
    __shared__ float4 sB[CHUNK];
    __shared__ float  sC[CHUNK];

    int chunk = blockIdx.x & (NCHUNK - 1);
    int grp   = (blockIdx.x >> 2) & 15;
    int b     = blockIdx.x >> 6;
    int t     = threadIdx.x;

    int base = b * Nn + chunk * CHUNK;
    if (t < CHUNK) {
        sA[t] = qA[base + t];
        sC[t] = qC[base + t];
    } else {
        sB[t - CHUNK] = qB[base + (t - CHUNK)];
    }
    __syncthreads();

    int pix = (grp << 8) | t;                 // 0..4095
    float fx = (float)(pix & 63);
    float fy = (float)(pix >> 6);
    float fx2 = fx * fx;
    float fxy = fx * fy;
    float fy2 = fy * fy;

    float accr = 0.0f, accg = 0.0f, accb = 0.0f;
#pragma unroll 8
    for (int n = 0; n < CHUNK; ++n) {
        float4 A  = sA[n];    // q0,q1,q2,q3
        float4 Bv = sB[n];    // q4,q5,ocr,ocg
        float  ob = sC[n];    // ocb
        float sgm = fmaf(A.y, fx, A.x);
        sgm = fmaf(A.z, fy, sgm);
        sgm = fmaf(A.w, fx2, sgm);
        sgm = fmaf(Bv.x, fxy, sgm);
        sgm = fmaf(Bv.y, fy2, sgm);
        float e = __builtin_amdgcn_exp2f(sgm);
        accr = fmaf(e, Bv.z, accr);
        accg = fmaf(e, Bv.w, accg);
        accb = fmaf(e, ob, accb);
    }

    size_t obase = (size_t)chunk * OUTSZ + (size_t)b * 3 * NPIX + (size_t)pix;
    partials[obase]            = accr;
    partials[obase + NPIX]     = accg;
    partials[obase + 2 * NPIX] = accb;
}

// Sum the 4 chunk partials into d_out. float4-vectorized, fully coalesced.
__global__ __launch_bounds__(256) void gs_reduce(const float* __restrict__ partials,
                                                 float* __restrict__ out) {
    int i = blockIdx.x * 256 + threadIdx.x;   // i in [0, OUTSZ/4)
    const float4* p0 = (const float4*)(partials);
    const float4* p1 = (const float4*)(partials + OUTSZ);
    const float4* p2 = (const float4*)(partials + 2 * OUTSZ);
    const float4* p3 = (const float4*)(partials + 3 * OUTSZ);
    float4 a = p0[i], b = p1[i], c = p2[i], d = p3[i];
    float4 r;
    r.x = (a.x + b.x) + (c.x + d.x);
    r.y = (a.y + b.y) + (c.y + d.y);
    r.z = (a.z + b.z) + (c.z + d.z);
    r.w = (a.w + b.w) + (c.w + d.w);
    ((float4*)out)[i] = r;
}

extern "C" void kernel_launch(void* const* d_in, const int* in_sizes, int n_in,
                              void* d_out, int out_size, void* d_ws, size_t ws_size,
                              hipStream_t stream) {
    const float* data    = (const float*)d_in[0];
    const float* opacity = (const float*)d_in[1];

    // workspace layout (floats): qA (4*16384) | qB (4*16384) | qC (16384) | partials
    float* wsf = (float*)d_ws;
    float4* qA = (float4*)wsf;                          // 256 KB
    float4* qB = (float4*)(wsf + 4 * Bb * Nn);          // 256 KB
    float*  qC = wsf + 8 * Bb * Nn;                     // 64 KB
    float*  partials = wsf + 9 * Bb * Nn;               // 6.3 MB
    float*  out = (float*)d_out;

    gs_prep<<<(Bb * Nn + 255) / 256, 256, 0, stream>>>(data, opacity, qA, qB, qC);
    gs_render<<<Bb * 16 * NCHUNK, 256, 0, stream>>>(qA, qB, qC, partials);
    gs_reduce<<<OUTSZ / 4 / 256, 256, 0, stream>>>(partials, out);
}